// Round 6
// baseline (291.021 us; speedup 1.0000x reference)
//
#include <hip/hip_runtime.h>
#include <math.h>

#define DIM   1024
#define HEADS 16
#define DH    64
#define ROT   128
#define BATCH 2
#define SEQ   2048
#define ROWS  (BATCH*SEQ)        // 4096
#define PCOLS (DIM + 2*DH)       // 1152 = [q(1024) | k(64) | v(64)] per side
// 1/sqrt(128) * log2(e): scores arrive pre-scaled for exp2 in attn
#define ASCALE (0.08838834764831845f * 1.4426950408889634f)

typedef short bf16x8 __attribute__((ext_vector_type(8)));
typedef float f32x16 __attribute__((ext_vector_type(16)));
typedef unsigned u32x2 __attribute__((ext_vector_type(2)));

static __device__ __forceinline__ unsigned short f2bf(float f) {
    union { float f; unsigned u; } v; v.f = f;
    unsigned r = v.u + 0x7fffu + ((v.u >> 16) & 1u);   // RNE (no NaN inputs here)
    return (unsigned short)(r >> 16);
}
static __device__ __forceinline__ float bf2f(unsigned short u) {
    union { unsigned u; float f; } v; v.u = (unsigned)u << 16;
    return v.f;
}

#define GL2LDS(gp, lp) __builtin_amdgcn_global_load_lds(                    \
    (const __attribute__((address_space(1))) void*)(gp),                    \
    (__attribute__((address_space(3))) void*)(lp), 16, 0, 0)
#define CFENCE() asm volatile("" ::: "memory")
#define WAIT_VM0()  __builtin_amdgcn_s_waitcnt(0xF70)   // vmcnt(0)

// ---------------------------------------------------------------------------
// Convert fp32 inputs -> bf16 staging buffers + rotary cos/sin table.
// ---------------------------------------------------------------------------
__global__ __launch_bounds__(256) void convert_kernel(
    const float* __restrict__ x, const float* __restrict__ a,
    const float* __restrict__ Wq_x, const float* __restrict__ Wkv_x,
    const float* __restrict__ Wq_a, const float* __restrict__ Wkv_a,
    unsigned short* __restrict__ xbf, unsigned short* __restrict__ wbf,
    float2* __restrict__ tbl)
{
    const int blk = blockIdx.x;
    const float LN1E4_64 = 0.14391156831213f;   // ln(10000)/64
    if (blk >= 2624) {                           // rotary table segment
        int local = blk - 2624;                  // 0..127
        int pos = local * 16 + (threadIdx.x >> 4);
        int i   = threadIdx.x & 15;
        #pragma unroll
        for (int j = 0; j < 4; j++) {
            int jd = i * 4 + j;
            float th = (float)pos * expf(-LN1E4_64 * (float)jd);
            float sn, cs; sincosf(th, &sn, &cs);
            tbl[pos * 64 + jd] = make_float2(cs, sn);
        }
        return;
    }
    const float* s; unsigned short* d; int seg0;
    if      (blk < 1024) { s = x;     d = xbf;           seg0 = 0;    }
    else if (blk < 2048) { s = a;     d = xbf + 4194304; seg0 = 1024; }
    else if (blk < 2304) { s = Wq_x;  d = wbf;           seg0 = 2048; }
    else if (blk < 2336) { s = Wkv_x; d = wbf + 1048576; seg0 = 2304; }
    else if (blk < 2592) { s = Wq_a;  d = wbf + 1179648; seg0 = 2336; }
    else                 { s = Wkv_a; d = wbf + 2228224; seg0 = 2592; }
    long lb = ((long)blk - seg0) * 1024;
    #pragma unroll
    for (int j = 0; j < 4; j++) {
        long idx = lb + j * 256 + threadIdx.x;
        float4 v = ((const float4*)s)[idx];
        ((ushort4*)d)[idx] = make_ushort4(f2bf(v.x), f2bf(v.y), f2bf(v.z), f2bf(v.w));
    }
}

// ---------------------------------------------------------------------------
// Fused GEMM + l2norm + scale + concat + rotary.
// Grid (mt=64, jt=9), 256 threads = 4 waves.  576 blocks -> 2.25/CU.
// LDS (bytes): A0@0(4K), A1@4096, B0@8192(8K), B1@16384 (24 KB).
// Tile tau in [0,64): side = tau>>5, k0 = (tau&31)*32.
// ---------------------------------------------------------------------------
__global__ __launch_bounds__(256, 4) void gemm_fuse_kernel(
    const unsigned short* __restrict__ xbf, const unsigned short* __restrict__ wbf,
    const float* __restrict__ qx_scale, const float* __restrict__ qa_scale,
    const float* __restrict__ kx_scale, const float* __restrict__ ka_scale,
    const float2* __restrict__ tbl,
    unsigned short* __restrict__ qbuf, unsigned short* __restrict__ kbuf,
    unsigned short* __restrict__ vbufT)
{
    const int mt = blockIdx.x, jt = blockIdx.y;
    __shared__ __align__(16) char scg[24576];
    const int tid  = threadIdx.x;
    const int wave = tid >> 6, lane = tid & 63;
    const int m = lane & 31, hl = lane >> 5;
    const int wr = wave >> 1, wc = wave & 1;

    f32x16 acc0[2], acc1[2];
    acc0[0] = 0.0f; acc0[1] = 0.0f; acc1[0] = 0.0f; acc1[1] = 0.0f;

    // A staging (1 issue): row arow (64 rows x 64B), granule XOR-swizzled src
    const int arow = tid >> 2;
    const int ag   = (tid & 3) ^ ((arow >> 1) & 3);
    const unsigned short* Asrc = xbf + ((size_t)mt * 64 + arow) * DIM + ag * 8;
    // B staging (2 issues): 128 rows x 4 granules
    const unsigned short* Bsrc[2];
    #pragma unroll
    for (int i = 0; i < 2; i++) {
        int fg = i * 256 + tid;
        int brow = fg >> 2;
        int bg = (fg & 3) ^ ((brow >> 1) & 3);
        Bsrc[i] = wbf + ((size_t)jt * 128 + brow) * DIM + bg * 8;
    }
    const unsigned adst = (unsigned)wave * 1024;   // wave-uniform LDS base

    // read-side byte offsets
    const int ra = wr * 32 + m;
    unsigned aoff[2], boff[2][2];
    #pragma unroll
    for (int kp = 0; kp < 2; kp++) {
        aoff[kp] = (unsigned)(ra * 64 + (((kp * 2 + hl) ^ ((ra >> 1) & 3)) << 4));
        #pragma unroll
        for (int j2 = 0; j2 < 2; j2++) {
            int rb = wc * 64 + j2 * 32 + m;
            boff[kp][j2] = (unsigned)(rb * 64 + (((kp * 2 + hl) ^ ((rb >> 1) & 3)) << 4));
        }
    }

    // stage tile 0 (side 0, k0 = 0) into buffer 0
    GL2LDS(Asrc, scg + adst);
    GL2LDS(Bsrc[0], scg + 8192 + adst);
    GL2LDS(Bsrc[1], scg + 8192 + 4096 + adst);

#define GEMM_STEP(ACC, BUF, T)                                                   \
  {                                                                              \
    CFENCE();                                                                    \
    WAIT_VM0();                                                                  \
    __builtin_amdgcn_s_barrier();                                                \
    CFENCE();                                                                    \
    if ((T) < 63) {                                                              \
      const int nt = (T) + 1;                                                    \
      const size_t so = (size_t)(nt >> 5);                                       \
      const int kk = (nt & 31) * 32;                                             \
      GL2LDS(Asrc + so * ((size_t)ROWS * DIM) + kk,                              \
             scg + ((BUF) ^ 1) * 4096 + adst);                                   \
      GL2LDS(Bsrc[0] + so * ((size_t)PCOLS * DIM) + kk,                          \
             scg + 8192 + ((BUF) ^ 1) * 8192 + adst);                            \
      GL2LDS(Bsrc[1] + so * ((size_t)PCOLS * DIM) + kk,                          \
             scg + 8192 + ((BUF) ^ 1) * 8192 + 4096 + adst);                     \
    }                                                                            \
    CFENCE();                                                                    \
    _Pragma("unroll")                                                            \
    for (int kp = 0; kp < 2; kp++) {                                             \
      bf16x8 af = *(const bf16x8*)(scg + (BUF) * 4096 + aoff[kp]);               \
      bf16x8 b0 = *(const bf16x8*)(scg + 8192 + (BUF) * 8192 + boff[kp][0]);     \
      bf16x8 b1 = *(const bf16x8*)(scg + 8192 + (BUF) * 8192 + boff[kp][1]);     \
      ACC[0] = __builtin_amdgcn_mfma_f32_32x32x16_bf16(af, b0, ACC[0], 0, 0, 0); \
      ACC[1] = __builtin_amdgcn_mfma_f32_32x32x16_bf16(af, b1, ACC[1], 0, 0, 0); \
    }                                                                            \
  }

    for (int tt = 0; tt < 32; tt += 2) { GEMM_STEP(acc0, 0, tt); GEMM_STEP(acc0, 1, tt + 1); }
    for (int tt = 32; tt < 64; tt += 2) { GEMM_STEP(acc1, 0, tt); GEMM_STEP(acc1, 1, tt + 1); }
#undef GEMM_STEP

    // ---------------- epilogue: norm + scale + rotary + store -------------
    const int rowbase = mt * 64 + wr * 32;
    const int bb = rowbase >> 11;            // batch, block-uniform

    if (jt < 8) {
        // ---- Q: head h = jt*2 + wc, dims d = j2*32 + m ----
        const int h = jt * 2 + wc;
        const float scx0 = qx_scale[h * DH + m], scx1 = qx_scale[h * DH + 32 + m];
        const float sca0 = qa_scale[h * DH + m], sca1 = qa_scale[h * DH + 32 + m];
        unsigned short* qbase = qbuf + ((size_t)(bb * HEADS + h)) * SEQ * ROT;
        #pragma unroll
        for (int r = 0; r < 16; r++) {
            float px = acc0[0][r] * acc0[0][r] + acc0[1][r] * acc0[1][r];
            float pa = acc1[0][r] * acc1[0][r] + acc1[1][r] * acc1[1][r];
            #pragma unroll
            for (int off = 1; off < 32; off <<= 1) {
                px += __shfl_xor(px, off);
                pa += __shfl_xor(pa, off);
            }
            float inx = 1.0f / fmaxf(sqrtf(px), 1e-12f);
            float ina = 1.0f / fmaxf(sqrtf(pa), 1e-12f);
            const int row = rowbase + (r & 3) + 8 * (r >> 2) + 4 * hl;
            const int pos = row & 2047;
            const float2* tp = tbl + pos * 64;
            unsigned short* qrow = qbase + (size_t)pos * ROT;
            #pragma unroll
            for (int j2 = 0; j2 < 2; j2++) {
                const int d = j2 * 32 + m;
                float qx = acc0[j2][r] * inx * (j2 ? scx1 : scx0);
                float qa = acc1[j2][r] * ina * (j2 ? sca1 : sca0);
                float2 cs = tp[d];
                qrow[d]      = f2bf((qx * cs.x - qa * cs.y) * ASCALE);
                qrow[DH + d] = f2bf((qa * cs.x + qx * cs.y) * ASCALE);
            }
        }
    } else if (wc == 0) {
        // ---- K: dims d = j2*32 + m, shared scale, no ASCALE ----
        const float scx0 = kx_scale[m], scx1 = kx_scale[32 + m];
        const float sca0 = ka_scale[m], sca1 = ka_scale[32 + m];
        unsigned short* kbase = kbuf + (size_t)bb * SEQ * ROT;
        #pragma unroll
        for (int r = 0; r < 16; r++) {
            float px = acc0[0][r] * acc0[0][r] + acc0[1][r] * acc0[1][r];
            float pa = acc1[0][r] * acc1[0][r] + acc1[1][r] * acc1[1][r];
            #pragma unroll
            for (int off = 1; off < 32; off <<= 1) {
                px += __shfl_xor(px, off);
                pa += __shfl_xor(pa, off);
            }
            float inx = 1.0f / fmaxf(sqrtf(px), 1e-12f);
            float ina = 1.0f / fmaxf(sqrtf(pa), 1e-12f);
            const int row = rowbase + (r & 3) + 8 * (r >> 2) + 4 * hl;
            const int pos = row & 2047;
            const float2* tp = tbl + pos * 64;
            unsigned short* krow = kbase + (size_t)pos * ROT;
            #pragma unroll
            for (int j2 = 0; j2 < 2; j2++) {
                const int d = j2 * 32 + m;
                float kx = acc0[j2][r] * inx * (j2 ? scx1 : scx0);
                float ka = acc1[j2][r] * ina * (j2 ? sca1 : sca0);
                float2 cs = tp[d];
                krow[d]      = f2bf(kx * cs.x - ka * cs.y);
                krow[DH + d] = f2bf(ka * cs.x + kx * cs.y);
            }
        }
    } else {
        // ---- V: exact bf16 copy, transposed store (x-side d<64, a-side d>=64)
        unsigned short* vb = vbufT + (size_t)bb * ROT * SEQ;
        #pragma unroll
        for (int r = 0; r < 16; r++) {
            const int row = rowbase + (r & 3) + 8 * (r >> 2) + 4 * hl;
            const int pos = row & 2047;
            #pragma unroll
            for (int j2 = 0; j2 < 2; j2++) {
                const int d = j2 * 32 + m;
                vb[(size_t)d * SEQ + pos]        = f2bf(acc0[j2][r]);
                vb[(size_t)(DH + d) * SEQ + pos] = f2bf(acc1[j2][r]);
            }
        }
    }
}

// ---------------------------------------------------------------------------
// MFMA flash attention (bf16, 32x32x16), KV-split x2.
// Each block handles 1024 keys in 32 tiles of KVBLK=32; LDS 32 KB ->
// 4 blocks/CU = 4 waves/SIMD (TLP was capped at 2).  Splits write
// unnormalized fp32 O + lsum; merge_kernel combines (exact: no-max exp is
// associative over key blocks).
// LDS (bytes): K0@0(8K), K1@8192, V0@16384(8K), V1@24576.
// ---------------------------------------------------------------------------
__global__ __launch_bounds__(256, 4) void attn_kernel(
    const unsigned short* __restrict__ qbuf,
    const unsigned short* __restrict__ kbuf,
    const unsigned short* __restrict__ vbufT,
    float* __restrict__ po0, float* __restrict__ po1, float* __restrict__ pl)
{
    const int qb = blockIdx.x, h = blockIdx.y;
    const int b = blockIdx.z & 1, s = blockIdx.z >> 1;
    __shared__ __align__(16) char sc_[32768];
    const char* sc = sc_;
    const int tid  = threadIdx.x;
    const int wave = tid >> 6, lane = tid & 63;
    const int m = lane & 31, hl = lane >> 5;
    const int q0 = qb * 128 + wave * 32;

    // Q resident (B-frag): chunk c covers d = c*16 + hl*8 + j
    bf16x8 qf[8];
    {
        const unsigned short* qp = qbuf + (((size_t)(b * HEADS + h)) * SEQ + q0 + m) * ROT + hl * 8;
        #pragma unroll
        for (int c = 0; c < 8; c++) qf[c] = *(const bf16x8*)(qp + c * 16);
    }

    f32x16 oacc[4];
    #pragma unroll
    for (int dt = 0; dt < 4; dt++) oacc[dt] = 0.0f;
    float lsum = 0.f;

    // Per-lane LDS byte offsets (buf 0 bases).
    // K tile: 32 key-rows x 256B;  V^T tile: 128 d-rows x 64B (4 granules).
    unsigned koff[8];
    #pragma unroll
    for (int c = 0; c < 8; c++)
        koff[c] = (unsigned)(m * 256 + (((2 * c + hl) ^ (m & 15)) << 4));
    unsigned voff[2];
    #pragma unroll
    for (int w = 0; w < 2; w++)
        voff[w] = (unsigned)(16384 + m * 64 + (((w * 2 + hl) ^ ((m >> 2) & 3)) << 4));

    const unsigned short* kb_ = kbuf  + (size_t)b * SEQ * ROT + (size_t)s * 1024 * ROT;
    const unsigned short* vb_ = vbufT + (size_t)b * ROT * SEQ + (size_t)s * 1024;

    // per-thread staging addresses (swizzle folded into the global source)
    const unsigned short* ksrc[2];
    const unsigned short* vsrc[2];
    unsigned ldst[2];
    #pragma unroll
    for (int i = 0; i < 2; i++) {
        int fg = i * 256 + tid;
        int krow = fg >> 4, kgr = fg & 15;             // K: 32 rows x 16 granules
        ksrc[i] = kb_ + (size_t)krow * ROT + ((kgr ^ (krow & 15)) << 3);
        int rv = fg >> 2, gv = fg & 3;                 // V^T: 128 rows x 4 granules
        vsrc[i] = vb_ + (size_t)rv * SEQ + ((gv ^ ((rv >> 2) & 3)) << 3);
        ldst[i] = (unsigned)(i * 4096 + wave * 1024);  // bytes, wave-uniform base
    }

    // stage tile 0 into buffer 0
    #pragma unroll
    for (int i = 0; i < 2; i++) {
        GL2LDS(ksrc[i], sc + ldst[i]);
        GL2LDS(vsrc[i], sc + 16384 + ldst[i]);
    }

#define ATTN_TILE(BUF, T)                                                            \
  {                                                                                  \
    CFENCE();                                                                        \
    WAIT_VM0();                                                                      \
    __builtin_amdgcn_s_barrier();                                                    \
    CFENCE();                                                                        \
    if ((T) < 31) {                        /* prefetch T+1 into alternate buffer */  \
      _Pragma("unroll")                                                              \
      for (int i = 0; i < 2; i++) {                                                  \
        GL2LDS(ksrc[i] + (size_t)((T) + 1) * 32 * ROT,                               \
               sc + ((BUF) ^ 1) * 8192 + ldst[i]);                                   \
        GL2LDS(vsrc[i] + (size_t)((T) + 1) * 32,                                     \
               sc + 16384 + ((BUF) ^ 1) * 8192 + ldst[i]);                           \
      }                                                                              \
    }                                                                                \
    CFENCE();                                                                        \
    f32x16 st = 0.0f;                                                                \
    __builtin_amdgcn_s_setprio(1);                                                   \
    _Pragma("unroll")                                                                \
    for (int c = 0; c < 8; c++) {                                                    \
      bf16x8 a0 = *(const bf16x8*)(sc + (BUF) * 8192 + koff[c]);                     \
      st = __builtin_amdgcn_mfma_f32_32x32x16_bf16(a0, qf[c], st, 0, 0, 0);          \
    }                                                                                \
    __builtin_amdgcn_s_setprio(0);                                                   \
    float p[16];                                                                     \
    _Pragma("unroll")                                                                \
    for (int r = 0; r < 16; r++) { p[r] = __builtin_amdgcn_exp2f(st[r]); lsum += p[r]; } \
    _Pragma("unroll")                                                                \
    for (int w = 0; w < 2; w++) {                                                    \
      unsigned pk0, pk1, pk2, pk3;                                                   \
      asm("v_cvt_pk_bf16_f32 %0, %1, %2" : "=v"(pk0) : "v"(p[8*w+0]), "v"(p[8*w+1])); \
      asm("v_cvt_pk_bf16_f32 %0, %1, %2" : "=v"(pk1) : "v"(p[8*w+2]), "v"(p[8*w+3])); \
      asm("v_cvt_pk_bf16_f32 %0, %1, %2" : "=v"(pk2) : "v"(p[8*w+4]), "v"(p[8*w+5])); \
      asm("v_cvt_pk_bf16_f32 %0, %1, %2" : "=v"(pk3) : "v"(p[8*w+6]), "v"(p[8*w+7])); \
      u32x2 s0 = __builtin_amdgcn_permlane32_swap(pk0, pk2, false, false);           \
      u32x2 s1 = __builtin_amdgcn_permlane32_swap(pk1, pk3, false, false);           \
      union { unsigned u[4]; bf16x8 v; } apu;                                        \
      apu.u[0] = s0[0]; apu.u[1] = s1[0]; apu.u[2] = s0[1]; apu.u[3] = s1[1];        \
      bf16x8 aP = apu.v;                                                             \
      __builtin_amdgcn_s_setprio(1);                                                 \
      _Pragma("unroll")                                                              \
      for (int dt = 0; dt < 4; dt++) {                                               \
        bf16x8 vf = *(const bf16x8*)(sc + (BUF) * 8192 + voff[w] + dt * 2048);       \
        oacc[dt] = __builtin_amdgcn_mfma_f32_32x32x16_bf16(aP, vf, oacc[dt], 0, 0, 0); \
      }                                                                              \
      __builtin_amdgcn_s_setprio(0);                                                 \
    }                                                                                \
  }

    for (int tt = 0; tt < 32; tt += 2) {
        ATTN_TILE(0, tt);
        ATTN_TILE(1, tt + 1);
    }
#undef ATTN_TILE

    lsum += __shfl_xor(lsum, 32);    // add other half-lane's keys
    float* pbase = s ? po1 : po0;
    float* ob = pbase + ((size_t)(b * SEQ + q0)) * (HEADS * ROT) + h * ROT + m;
    #pragma unroll
    for (int r = 0; r < 16; r++) {
        int qrow = (r & 3) + 8 * (r >> 2) + 4 * hl;
        float* orow = ob + (size_t)qrow * (HEADS * ROT);
        #pragma unroll
        for (int dt = 0; dt < 4; dt++) orow[dt * 32] = oacc[dt][r];
    }
    if (lane < 32)
        pl[(((size_t)s * BATCH + b) * HEADS + h) * SEQ + q0 + m] = lsum;
}

// ---------------------------------------------------------------------------
// Merge the two KV-split partials: out = (o0 + o1) / (l0 + l1).
// out layout [b][pos][h][d]; po1 identical; pl [s][b][h][pos].
// Total float4s = B*SEQ*HEADS*ROT/4 = 2,097,152 -> grid 2048 x 1024 f4/blk.
// ---------------------------------------------------------------------------
__global__ __launch_bounds__(256) void merge_kernel(
    float* __restrict__ out, const float* __restrict__ po1,
    const float* __restrict__ pl)
{
    const int tid = threadIdx.x;
    const size_t base = (size_t)blockIdx.x * 1024 + tid;   // float4 index
    #pragma unroll
    for (int j = 0; j < 4; j++) {
        size_t fi = base + (size_t)j * 256;
        size_t ei = fi * 4;
        int b   = (int)(ei >> 22);            // 2048*2048 elems per batch
        int rem = (int)(ei & 4194303);
        int pos = rem >> 11;
        int h   = (rem >> 7) & 15;
        float l0 = pl[((size_t)(b)*HEADS + h) * SEQ + pos];
        float l1 = pl[((size_t)(2 + b) * HEADS + h) * SEQ + pos];
        float inv = 1.0f / (l0 + l1);
        float4 o0 = ((const float4*)out)[fi];
        float4 o1 = ((const float4*)po1)[fi];
        float4 r;
        r.x = (o0.x + o1.x) * inv;
        r.y = (o0.y + o1.y) * inv;
        r.z = (o0.z + o1.z) * inv;
        r.w = (o0.w + o1.w) * inv;
        ((float4*)out)[fi] = r;
    }
}

// ---------------------------------------------------------------------------
// Workspace layout (bytes) — peak 52,953,088 <= 60,293,120 used previously:
//   qbuf  @ 0          (16,777,216)   written by gemm_fuse, read by attn
//   kbuf  @ 16,777,216 ( 1,048,576)
//   vbufT @ 17,825,792 ( 1,048,576)
//   pl    @ 18,874,368 (   524,288)   written by attn, read by merge
//   xbf   @ 19,398,656 (16,777,216)   convert -> gemm_fuse (dead at attn)
//   wbf   @ 36,175,872 ( 4,718,592)   convert -> gemm_fuse (dead at attn)
//   tbl   @ 40,894,464 ( 1,048,576)   convert -> gemm_fuse (dead at attn)
//   po1   @ 19,398,656 (33,554,432)   ALIASES xbf/wbf/tbl — attn runs after
//                                     gemm_fuse (stream order), so safe.
// ---------------------------------------------------------------------------
extern "C" void kernel_launch(void* const* d_in, const int* in_sizes, int n_in,
                              void* d_out, int out_size, void* d_ws, size_t ws_size,
                              hipStream_t stream) {
    (void)in_sizes; (void)n_in; (void)out_size; (void)ws_size;
    const float* x        = (const float*)d_in[0];
    const float* a        = (const float*)d_in[1];
    const float* Wq_x     = (const float*)d_in[2];
    const float* Wkv_x    = (const float*)d_in[3];
    const float* Wq_a     = (const float*)d_in[4];
    const float* Wkv_a    = (const float*)d_in[5];
    const float* qx_scale = (const float*)d_in[6];
    const float* qa_scale = (const float*)d_in[7];
    const float* kx_scale = (const float*)d_in[8];
    const float* ka_scale = (const float*)d_in[9];
    float* out = (float*)d_out;

    char* ws = (char*)d_ws;
    unsigned short* qbuf  = (unsigned short*)(ws);
    unsigned short* kbuf  = (unsigned short*)(ws + 16777216);
    unsigned short* vbufT = (unsigned short*)(ws + 17825792);
    float*          pl    = (float*)(ws + 18874368);
    unsigned short* xbf   = (unsigned short*)(ws + 19398656);
    unsigned short* wbf   = (unsigned short*)(ws + 36175872);
    float2*         tbl   = (float2*)(ws + 40894464);
    float*          po1   = (float*)(ws + 19398656);   // aliases xbf/wbf/tbl

    convert_kernel<<<dim3(2752), 256, 0, stream>>>(x, a, Wq_x, Wkv_x, Wq_a, Wkv_a,
                                                   xbf, wbf, tbl);
    gemm_fuse_kernel<<<dim3(64, 9), 256, 0, stream>>>(xbf, wbf,
                                                      qx_scale, qa_scale, kx_scale, ka_scale,
                                                      tbl, qbuf, kbuf, vbufT);
    attn_kernel<<<dim3(SEQ / 128, HEADS, 2 * BATCH), 256, 0, stream>>>(qbuf, kbuf, vbufT,
                                                                       out, po1, pl);
    merge_kernel<<<dim3(2048), 256, 0, stream>>>(out, po1, pl);
}

// Round 7
// 223.132 us; speedup vs baseline: 1.3043x; 1.3043x over previous
//
#include <hip/hip_runtime.h>
#include <math.h>

#define DIM   1024
#define HEADS 16
#define DH    64
#define ROT   128
#define BATCH 2
#define SEQ   2048
#define ROWS  (BATCH*SEQ)        // 4096
#define PCOLS (DIM + 2*DH)       // 1152 = [q(1024) | k(64) | v(64)] per side
// 1/sqrt(128) * log2(e): scores arrive pre-scaled for exp2 in attn
#define ASCALE (0.08838834764831845f * 1.4426950408889634f)

typedef short bf16x8 __attribute__((ext_vector_type(8)));
typedef float f32x16 __attribute__((ext_vector_type(16)));
typedef unsigned u32x2 __attribute__((ext_vector_type(2)));

static __device__ __forceinline__ unsigned short f2bf(float f) {
    union { float f; unsigned u; } v; v.f = f;
    unsigned r = v.u + 0x7fffu + ((v.u >> 16) & 1u);   // RNE (no NaN inputs here)
    return (unsigned short)(r >> 16);
}
static __device__ __forceinline__ float bf2f(unsigned short u) {
    union { unsigned u; float f; } v; v.u = (unsigned)u << 16;
    return v.f;
}

#define GL2LDS(gp, lp) __builtin_amdgcn_global_load_lds(                    \
    (const __attribute__((address_space(1))) void*)(gp),                    \
    (__attribute__((address_space(3))) void*)(lp), 16, 0, 0)
#define CFENCE() asm volatile("" ::: "memory")
// s_waitcnt imm: vmcnt[3:0]|[15:14], expcnt[6:4], lgkmcnt[11:8]; others maxed
#define WAIT_VM3()  __builtin_amdgcn_s_waitcnt(0xF73)   // vmcnt(3)
#define WAIT_VM0()  __builtin_amdgcn_s_waitcnt(0xF70)   // vmcnt(0)

// ---------------------------------------------------------------------------
// Convert fp32 inputs -> bf16 staging buffers + rotary cos/sin table.
// ---------------------------------------------------------------------------
__global__ __launch_bounds__(256) void convert_kernel(
    const float* __restrict__ x, const float* __restrict__ a,
    const float* __restrict__ Wq_x, const float* __restrict__ Wkv_x,
    const float* __restrict__ Wq_a, const float* __restrict__ Wkv_a,
    unsigned short* __restrict__ xbf, unsigned short* __restrict__ wbf,
    float2* __restrict__ tbl)
{
    const int blk = blockIdx.x;
    const float LN1E4_64 = 0.14391156831213f;   // ln(10000)/64
    if (blk >= 2624) {                           // rotary table segment
        int local = blk - 2624;                  // 0..127
        int pos = local * 16 + (threadIdx.x >> 4);
        int i   = threadIdx.x & 15;
        #pragma unroll
        for (int j = 0; j < 4; j++) {
            int jd = i * 4 + j;
            float th = (float)pos * expf(-LN1E4_64 * (float)jd);
            float sn, cs; sincosf(th, &sn, &cs);
            tbl[pos * 64 + jd] = make_float2(cs, sn);
        }
        return;
    }
    const float* s; unsigned short* d; int seg0;
    if      (blk < 1024) { s = x;     d = xbf;           seg0 = 0;    }
    else if (blk < 2048) { s = a;     d = xbf + 4194304; seg0 = 1024; }
    else if (blk < 2304) { s = Wq_x;  d = wbf;           seg0 = 2048; }
    else if (blk < 2336) { s = Wkv_x; d = wbf + 1048576; seg0 = 2304; }
    else if (blk < 2592) { s = Wq_a;  d = wbf + 1179648; seg0 = 2336; }
    else                 { s = Wkv_a; d = wbf + 2228224; seg0 = 2592; }
    long lb = ((long)blk - seg0) * 1024;
    #pragma unroll
    for (int j = 0; j < 4; j++) {
        long idx = lb + j * 256 + threadIdx.x;
        float4 v = ((const float4*)s)[idx];
        ((ushort4*)d)[idx] = make_ushort4(f2bf(v.x), f2bf(v.y), f2bf(v.z), f2bf(v.w));
    }
}

// ---------------------------------------------------------------------------
// Fused GEMM + l2norm + scale + concat + rotary.
// R8: depth-2 prefetch with 4 LDS buffers + counted vmcnt(3) (T4).  The old
// depth-1 vmcnt(0) schedule gave each load batch only ~1 compute phase of
// slack vs ~200-400cy L2 latency at 2.25 blocks/CU.  Now tile T's 3 loads
// are the oldest 3 of 6 outstanding -> vmcnt(3) leaves T+1's in flight
// across the barrier; each batch gets 2 compute phases + 2 barriers of slack.
// LDS (bytes): A buffers 4x4096 @ 0, B buffers 4x8192 @ 16384 (48 KB).
// Tile T in [0,64): side = T>>5, k0 = (T&31)*32.
// ---------------------------------------------------------------------------
__global__ __launch_bounds__(256, 3) void gemm_fuse_kernel(
    const unsigned short* __restrict__ xbf, const unsigned short* __restrict__ wbf,
    const float* __restrict__ qx_scale, const float* __restrict__ qa_scale,
    const float* __restrict__ kx_scale, const float* __restrict__ ka_scale,
    const float2* __restrict__ tbl,
    unsigned short* __restrict__ qbuf, unsigned short* __restrict__ kbuf,
    unsigned short* __restrict__ vbufT)
{
    const int mt = blockIdx.x, jt = blockIdx.y;
    __shared__ __align__(16) char scg[49152];
    const int tid  = threadIdx.x;
    const int wave = tid >> 6, lane = tid & 63;
    const int m = lane & 31, hl = lane >> 5;
    const int wr = wave >> 1, wc = wave & 1;

    f32x16 acc0[2], acc1[2];
    acc0[0] = 0.0f; acc0[1] = 0.0f; acc1[0] = 0.0f; acc1[1] = 0.0f;

    // A staging (1 issue): row arow (64 rows x 64B), granule XOR-swizzled src
    const int arow = tid >> 2;
    const int ag   = (tid & 3) ^ ((arow >> 1) & 3);
    const unsigned short* Asrc = xbf + ((size_t)mt * 64 + arow) * DIM + ag * 8;
    // B staging (2 issues): 128 rows x 4 granules
    const unsigned short* Bsrc[2];
    #pragma unroll
    for (int i = 0; i < 2; i++) {
        int fg = i * 256 + tid;
        int brow = fg >> 2;
        int bg = (fg & 3) ^ ((brow >> 1) & 3);
        Bsrc[i] = wbf + ((size_t)jt * 128 + brow) * DIM + bg * 8;
    }
    const unsigned adst = (unsigned)wave * 1024;   // wave-uniform LDS base

    // read-side byte offsets
    const int ra = wr * 32 + m;
    unsigned aoff[2], boff[2][2];
    #pragma unroll
    for (int kp = 0; kp < 2; kp++) {
        aoff[kp] = (unsigned)(ra * 64 + (((kp * 2 + hl) ^ ((ra >> 1) & 3)) << 4));
        #pragma unroll
        for (int j2 = 0; j2 < 2; j2++) {
            int rb = wc * 64 + j2 * 32 + m;
            boff[kp][j2] = (unsigned)(rb * 64 + (((kp * 2 + hl) ^ ((rb >> 1) & 3)) << 4));
        }
    }

    // prologue: stage tiles 0 and 1 into buffers 0 and 1 (6 loads in flight)
    GL2LDS(Asrc, scg + adst);
    GL2LDS(Bsrc[0], scg + 16384 + adst);
    GL2LDS(Bsrc[1], scg + 16384 + 4096 + adst);
    GL2LDS(Asrc + 32, scg + 4096 + adst);
    GL2LDS(Bsrc[0] + 32, scg + 16384 + 8192 + adst);
    GL2LDS(Bsrc[1] + 32, scg + 16384 + 8192 + 4096 + adst);

#define GEMM_STEP(ACC, BUF, T)                                                   \
  {                                                                              \
    CFENCE();                                                                    \
    if ((T) < 63) WAIT_VM3(); else WAIT_VM0();  /* T's 3 = oldest of <=6 */      \
    __builtin_amdgcn_s_barrier();                                                \
    CFENCE();                                                                    \
    if ((T) < 62) {                       /* prefetch T+2, depth-2 pipeline */   \
      const int nt = (T) + 2;                                                    \
      const size_t so = (size_t)(nt >> 5);                                       \
      const int kk = (nt & 31) * 32;                                             \
      GL2LDS(Asrc + so * ((size_t)ROWS * DIM) + kk,                              \
             scg + ((((T) + 2) & 3)) * 4096 + adst);                             \
      GL2LDS(Bsrc[0] + so * ((size_t)PCOLS * DIM) + kk,                          \
             scg + 16384 + ((((T) + 2) & 3)) * 8192 + adst);                     \
      GL2LDS(Bsrc[1] + so * ((size_t)PCOLS * DIM) + kk,                          \
             scg + 16384 + ((((T) + 2) & 3)) * 8192 + 4096 + adst);              \
    }                                                                            \
    CFENCE();                                                                    \
    _Pragma("unroll")                                                            \
    for (int kp = 0; kp < 2; kp++) {                                             \
      bf16x8 af = *(const bf16x8*)(scg + (BUF) * 4096 + aoff[kp]);               \
      bf16x8 b0 = *(const bf16x8*)(scg + 16384 + (BUF) * 8192 + boff[kp][0]);    \
      bf16x8 b1 = *(const bf16x8*)(scg + 16384 + (BUF) * 8192 + boff[kp][1]);    \
      ACC[0] = __builtin_amdgcn_mfma_f32_32x32x16_bf16(af, b0, ACC[0], 0, 0, 0); \
      ACC[1] = __builtin_amdgcn_mfma_f32_32x32x16_bf16(af, b1, ACC[1], 0, 0, 0); \
    }                                                                            \
  }

    for (int tt = 0; tt < 32; tt += 4) {
        GEMM_STEP(acc0, 0, tt);     GEMM_STEP(acc0, 1, tt + 1);
        GEMM_STEP(acc0, 2, tt + 2); GEMM_STEP(acc0, 3, tt + 3);
    }
    for (int tt = 32; tt < 64; tt += 4) {
        GEMM_STEP(acc1, 0, tt);     GEMM_STEP(acc1, 1, tt + 1);
        GEMM_STEP(acc1, 2, tt + 2); GEMM_STEP(acc1, 3, tt + 3);
    }
#undef GEMM_STEP

    // ---------------- epilogue: norm + scale + rotary + store -------------
    const int rowbase = mt * 64 + wr * 32;
    const int bb = rowbase >> 11;            // batch, block-uniform

    if (jt < 8) {
        // ---- Q: head h = jt*2 + wc, dims d = j2*32 + m ----
        const int h = jt * 2 + wc;
        const float scx0 = qx_scale[h * DH + m], scx1 = qx_scale[h * DH + 32 + m];
        const float sca0 = qa_scale[h * DH + m], sca1 = qa_scale[h * DH + 32 + m];
        unsigned short* qbase = qbuf + ((size_t)(bb * HEADS + h)) * SEQ * ROT;
        #pragma unroll
        for (int r = 0; r < 16; r++) {
            float px = acc0[0][r] * acc0[0][r] + acc0[1][r] * acc0[1][r];
            float pa = acc1[0][r] * acc1[0][r] + acc1[1][r] * acc1[1][r];
            #pragma unroll
            for (int off = 1; off < 32; off <<= 1) {
                px += __shfl_xor(px, off);
                pa += __shfl_xor(pa, off);
            }
            float inx = 1.0f / fmaxf(sqrtf(px), 1e-12f);
            float ina = 1.0f / fmaxf(sqrtf(pa), 1e-12f);
            const int row = rowbase + (r & 3) + 8 * (r >> 2) + 4 * hl;
            const int pos = row & 2047;
            const float2* tp = tbl + pos * 64;
            unsigned short* qrow = qbase + (size_t)pos * ROT;
            #pragma unroll
            for (int j2 = 0; j2 < 2; j2++) {
                const int d = j2 * 32 + m;
                float qx = acc0[j2][r] * inx * (j2 ? scx1 : scx0);
                float qa = acc1[j2][r] * ina * (j2 ? sca1 : sca0);
                float2 cs = tp[d];
                qrow[d]      = f2bf((qx * cs.x - qa * cs.y) * ASCALE);
                qrow[DH + d] = f2bf((qa * cs.x + qx * cs.y) * ASCALE);
            }
        }
    } else if (wc == 0) {
        // ---- K: dims d = j2*32 + m, shared scale, no ASCALE ----
        const float scx0 = kx_scale[m], scx1 = kx_scale[32 + m];
        const float sca0 = ka_scale[m], sca1 = ka_scale[32 + m];
        unsigned short* kbase = kbuf + (size_t)bb * SEQ * ROT;
        #pragma unroll
        for (int r = 0; r < 16; r++) {
            float px = acc0[0][r] * acc0[0][r] + acc0[1][r] * acc0[1][r];
            float pa = acc1[0][r] * acc1[0][r] + acc1[1][r] * acc1[1][r];
            #pragma unroll
            for (int off = 1; off < 32; off <<= 1) {
                px += __shfl_xor(px, off);
                pa += __shfl_xor(pa, off);
            }
            float inx = 1.0f / fmaxf(sqrtf(px), 1e-12f);
            float ina = 1.0f / fmaxf(sqrtf(pa), 1e-12f);
            const int row = rowbase + (r & 3) + 8 * (r >> 2) + 4 * hl;
            const int pos = row & 2047;
            const float2* tp = tbl + pos * 64;
            unsigned short* krow = kbase + (size_t)pos * ROT;
            #pragma unroll
            for (int j2 = 0; j2 < 2; j2++) {
                const int d = j2 * 32 + m;
                float kx = acc0[j2][r] * inx * (j2 ? scx1 : scx0);
                float ka = acc1[j2][r] * ina * (j2 ? sca1 : sca0);
                float2 cs = tp[d];
                krow[d]      = f2bf(kx * cs.x - ka * cs.y);
                krow[DH + d] = f2bf(ka * cs.x + kx * cs.y);
            }
        }
    } else {
        // ---- V: exact bf16 copy, transposed store (x-side d<64, a-side d>=64)
        unsigned short* vb = vbufT + (size_t)bb * ROT * SEQ;
        #pragma unroll
        for (int r = 0; r < 16; r++) {
            const int row = rowbase + (r & 3) + 8 * (r >> 2) + 4 * hl;
            const int pos = row & 2047;
            #pragma unroll
            for (int j2 = 0; j2 < 2; j2++) {
                const int d = j2 * 32 + m;
                vb[(size_t)d * SEQ + pos]        = f2bf(acc0[j2][r]);
                vb[(size_t)(DH + d) * SEQ + pos] = f2bf(acc1[j2][r]);
            }
        }
    }
}

// ---------------------------------------------------------------------------
// MFMA flash attention (bf16, 32x32x16), double-buffered pipeline.
// REVERTED to the R6 known-good (75 µs, verified twice): 512 blocks x 4
// waves, KVBLK=64, 64 KB LDS, single barrier per tile, prefetch issued after
// the barrier, direct normalized write to out.  (KV-split x2 was refuted in
// R6 bench: occupancy 18->42% as predicted, but 67 MB of fp32 partials cost
// 2x via write-allocate -> FETCH 16->125 MB, dur 75->148 µs.)
// Layout of smem (bytes): K0@0, K1@16384, V0@32768, V1@49152.
// ---------------------------------------------------------------------------
__global__ __launch_bounds__(256, 2) void attn_kernel(
    const unsigned short* __restrict__ qbuf,
    const unsigned short* __restrict__ kbuf,
    const unsigned short* __restrict__ vbufT,
    float* __restrict__ out)
{
    const int qb = blockIdx.x, h = blockIdx.y, b = blockIdx.z;
    __shared__ __align__(16) unsigned short smem[32768];   // 64 KB
    const char* sc = (const char*)smem;
    const int tid  = threadIdx.x;
    const int wave = tid >> 6, lane = tid & 63;
    const int m = lane & 31, hl = lane >> 5;
    const int q0 = qb * 128 + wave * 32;

    // Q resident (B-frag): chunk c covers d = c*16 + hl*8 + j
    bf16x8 qf[8];
    {
        const unsigned short* qp = qbuf + (((size_t)(b * HEADS + h)) * SEQ + q0 + m) * ROT + hl * 8;
        #pragma unroll
        for (int c = 0; c < 8; c++) qf[c] = *(const bf16x8*)(qp + c * 16);
    }

    f32x16 oacc[4];
    #pragma unroll
    for (int dt = 0; dt < 4; dt++) oacc[dt] = 0.0f;
    float lsum = 0.f;

    // Precomputed per-lane LDS byte offsets (buf=0, kg=0, dt=0 bases).
    unsigned koff[8];
    #pragma unroll
    for (int c = 0; c < 8; c++)
        koff[c] = (unsigned)(m * 256 + (((2 * c + hl) ^ (m & 15)) << 4));
    unsigned voff[2][2];
    #pragma unroll
    for (int kg = 0; kg < 2; kg++)
        #pragma unroll
        for (int w = 0; w < 2; w++)
            voff[kg][w] = (unsigned)(32768 + m * 128 +
                                     (((kg * 4 + w * 2 + hl) ^ ((m >> 2) & 7)) << 4));

    const unsigned short* kb_ = kbuf  + (size_t)b * SEQ * ROT;
    const unsigned short* vb_ = vbufT + (size_t)b * ROT * SEQ;

    // per-thread staging addresses (swizzle folded into the global source)
    const unsigned short* ksrc[4];
    const unsigned short* vsrc[4];
    unsigned ldst[4];
    #pragma unroll
    for (int i = 0; i < 4; i++) {
        int fg = i * 256 + tid;
        int krow = fg >> 4, kgr = fg & 15;                // K: 64 rows x 16 granules
        ksrc[i] = kb_ + (size_t)krow * ROT + ((kgr ^ (krow & 15)) << 3);
        int rv = fg >> 3, gv = fg & 7;                    // V^T: 128 rows x 8 granules
        vsrc[i] = vb_ + (size_t)rv * SEQ + ((gv ^ ((rv >> 2) & 7)) << 3);
        ldst[i] = (unsigned)(i * 256 + wave * 64) * 16;   // bytes, wave-uniform base
    }

    // stage tile 0 into buffer 0
    #pragma unroll
    for (int i = 0; i < 4; i++) {
        GL2LDS(ksrc[i], sc + ldst[i]);
        GL2LDS(vsrc[i], sc + 32768 + ldst[i]);
    }

#define ATTN_TILE(BUF, T)                                                            \
  {                                                                                  \
    CFENCE();                                                                        \
    WAIT_VM0();                                                                      \
    __builtin_amdgcn_s_barrier();                                                    \
    CFENCE();                                                                        \
    if ((T) < 31) {                        /* prefetch T+1 into alternate buffer */  \
      _Pragma("unroll")                                                              \
      for (int i = 0; i < 4; i++) {                                                  \
        GL2LDS(ksrc[i] + (size_t)((T) + 1) * 64 * ROT,                               \
               sc + ((BUF) ^ 1) * 16384 + ldst[i]);                                  \
        GL2LDS(vsrc[i] + ((T) + 1) * 64,                                             \
               sc + 32768 + ((BUF) ^ 1) * 16384 + ldst[i]);                          \
      }                                                                              \
    }                                                                                \
    CFENCE();                                                                        \
    f32x16 st0 = 0.0f, st1 = 0.0f;                                                   \
    __builtin_amdgcn_s_setprio(1);                                                   \
    _Pragma("unroll")                                                                \
    for (int c = 0; c < 8; c++) {                                                    \
      bf16x8 a0 = *(const bf16x8*)(sc + (BUF) * 16384 + koff[c]);                    \
      st0 = __builtin_amdgcn_mfma_f32_32x32x16_bf16(a0, qf[c], st0, 0, 0, 0);        \
    }                                                                                \
    _Pragma("unroll")                                                                \
    for (int c = 0; c < 8; c++) {                                                    \
      bf16x8 a1 = *(const bf16x8*)(sc + (BUF) * 16384 + 8192 + koff[c]);             \
      st1 = __builtin_amdgcn_mfma_f32_32x32x16_bf16(a1, qf[c], st1, 0, 0, 0);        \
    }                                                                                \
    __builtin_amdgcn_s_setprio(0);                                                   \
    _Pragma("unroll")                                                                \
    for (int kg = 0; kg < 2; kg++) {                                                 \
      float p[16];                                                                   \
      _Pragma("unroll")                                                              \
      for (int r = 0; r < 16; r++) {                                                 \
        float sv = kg ? st1[r] : st0[r];                                             \
        p[r] = __builtin_amdgcn_exp2f(sv); lsum += p[r];                             \
      }                                                                              \
      __builtin_amdgcn_s_setprio(1);                                                 \
      _Pragma("unroll")                                                              \
      for (int w = 0; w < 2; w++) {                                                  \
        unsigned pk0, pk1, pk2, pk3;                                                 \
        asm("v_cvt_pk_bf16_f32 %0, %1, %2" : "=v"(pk0) : "v"(p[8*w+0]), "v"(p[8*w+1])); \
        asm("v_cvt_pk_bf16_f32 %0, %1, %2" : "=v"(pk1) : "v"(p[8*w+2]), "v"(p[8*w+3])); \
        asm("v_cvt_pk_bf16_f32 %0, %1, %2" : "=v"(pk2) : "v"(p[8*w+4]), "v"(p[8*w+5])); \
        asm("v_cvt_pk_bf16_f32 %0, %1, %2" : "=v"(pk3) : "v"(p[8*w+6]), "v"(p[8*w+7])); \
        u32x2 s0 = __builtin_amdgcn_permlane32_swap(pk0, pk2, false, false);         \
        u32x2 s1 = __builtin_amdgcn_permlane32_swap(pk1, pk3, false, false);         \
        union { unsigned u[4]; bf16x8 v; } apu;                                      \
        apu.u[0] = s0[0]; apu.u[1] = s1[0]; apu.u[2] = s0[1]; apu.u[3] = s1[1];      \
        bf16x8 aP = apu.v;                                                           \
        _Pragma("unroll")                                                            \
        for (int dt = 0; dt < 4; dt++) {                                             \
          bf16x8 vf = *(const bf16x8*)(sc + (BUF) * 16384 + voff[kg][w] + dt * 4096);\
          oacc[dt] = __builtin_amdgcn_mfma_f32_32x32x16_bf16(aP, vf, oacc[dt], 0, 0, 0); \
        }                                                                            \
      }                                                                              \
      __builtin_amdgcn_s_setprio(0);                                                 \
    }                                                                                \
  }

    for (int tt = 0; tt < 32; tt += 2) {
        ATTN_TILE(0, tt);
        ATTN_TILE(1, tt + 1);
    }
#undef ATTN_TILE

    lsum += __shfl_xor(lsum, 32);    // add other half-lane's keys
    float* ob = out + ((size_t)(b * SEQ + q0)) * (HEADS * ROT) + h * ROT + m;
    #pragma unroll
    for (int r = 0; r < 16; r++) {
        int qrow = (r & 3) + 8 * (r >> 2) + 4 * hl;
        float linv = 1.0f / __shfl(lsum, qrow);
        float* orow = ob + (size_t)qrow * (HEADS * ROT);
        #pragma unroll
        for (int dt = 0; dt < 4; dt++) orow[dt * 32] = oacc[dt][r] * linv;
    }
}

// ---------------------------------------------------------------------------
// Workspace layout (bytes):
//   qbuf  @ 0          (16,777,216)
//   kbuf  @ 16,777,216 ( 1,048,576)
//   vbufT @ 17,825,792 ( 1,048,576)
//   xbf   @ 19,398,656 (16,777,216)
//   wbf   @ 36,175,872 ( 4,718,592)
//   tbl   @ 40,894,464 ( 1,048,576)
// ---------------------------------------------------------------------------
extern "C" void kernel_launch(void* const* d_in, const int* in_sizes, int n_in,
                              void* d_out, int out_size, void* d_ws, size_t ws_size,
                              hipStream_t stream) {
    (void)in_sizes; (void)n_in; (void)out_size; (void)ws_size;
    const float* x        = (const float*)d_in[0];
    const float* a        = (const float*)d_in[1];
    const float* Wq_x     = (const float*)d_in[2];
    const float* Wkv_x    = (const float*)d_in[3];
    const float* Wq_a     = (const float*)d_in[4];
    const float* Wkv_a    = (const float*)d_in[5];
    const float* qx_scale = (const float*)d_in[6];
    const float* qa_scale = (const float*)d_in[7];
    const float* kx_scale = (const float*)d_in[8];
    const float* ka_scale = (const float*)d_in[9];
    float* out = (float*)d_out;

    char* ws = (char*)d_ws;
    unsigned short* qbuf  = (unsigned short*)(ws);
    unsigned short* kbuf  = (unsigned short*)(ws + 16777216);
    unsigned short* vbufT = (unsigned short*)(ws + 17825792);
    unsigned short* xbf   = (unsigned short*)(ws + 19398656);
    unsigned short* wbf   = (unsigned short*)(ws + 36175872);
    float2*         tbl   = (float2*)(ws + 40894464);

    convert_kernel<<<dim3(2752), 256, 0, stream>>>(x, a, Wq_x, Wkv_x, Wq_a, Wkv_a,
                                                   xbf, wbf, tbl);
    gemm_fuse_kernel<<<dim3(64, 9), 256, 0, stream>>>(xbf, wbf,
                                                      qx_scale, qa_scale, kx_scale, ka_scale,
                                                      tbl, qbuf, kbuf, vbufT);
    attn_kernel<<<dim3(SEQ / 128, HEADS, BATCH), 256, 0, stream>>>(qbuf, kbuf, vbufT, out);
}